// Round 3
// baseline (1494.226 us; speedup 1.0000x reference)
//
#include <hip/hip_runtime.h>

#define HW 65536
#define STRIDE 68   // padded LDS row stride in floats (16B-aligned, breaks bank degeneracy)

// dst[r][c] = sum_k src[r][k] * W[k][c] + bias[c]   (64x64 weights, 64-row tile)
// Each lane owns one output column (lane_c); each 64-lane wave owns 16 rows (group g).
// K-loop is a DYNAMIC outer loop (keeps code size small); row loop is fully
// unrolled so acc[16] stays constant-indexed in registers.
// MODE 0: store to dst LDS; MODE 1: accumulate into acc16 regs; MODE 2: store dst - sub
template<int MODE>
__device__ __forceinline__ void mat64(float* __restrict__ dst,
                                      const float* __restrict__ src,
                                      const float* __restrict__ W,
                                      const float* __restrict__ bias,
                                      const float* __restrict__ sub,
                                      float* __restrict__ acc16,
                                      int lane_c, int g)
{
    float acc[16];
    #pragma unroll
    for (int i = 0; i < 16; ++i) acc[i] = 0.f;

    const float* __restrict__ rows = src + g * 16 * STRIDE;

    for (int k4 = 0; k4 < 16; ++k4) {          // dynamic: 4 k-values per iteration
        const float w0 = W[(4 * k4 + 0) * 64 + lane_c];
        const float w1 = W[(4 * k4 + 1) * 64 + lane_c];
        const float w2 = W[(4 * k4 + 2) * 64 + lane_c];
        const float w3 = W[(4 * k4 + 3) * 64 + lane_c];
        #pragma unroll
        for (int r0 = 0; r0 < 16; ++r0) {
            // wave-uniform LDS address -> broadcast, conflict-free
            const float4 a = *(const float4*)(rows + r0 * STRIDE + 4 * k4);
            float v = acc[r0];
            v = fmaf(a.x, w0, v);
            v = fmaf(a.y, w1, v);
            v = fmaf(a.z, w2, v);
            acc[r0] = fmaf(a.w, w3, v);
        }
    }

    const float bv = bias[lane_c];
    #pragma unroll
    for (int r0 = 0; r0 < 16; ++r0) {
        const int r = g * 16 + r0;
        const float v = acc[r0] + bv;
        if (MODE == 0)      dst[r * STRIDE + lane_c] = v;
        else if (MODE == 1) acc16[r0] += v;
        else                dst[r * STRIDE + lane_c] = v - sub[r * STRIDE + lane_c];
    }
}

__global__ __launch_bounds__(256, 2)
void hpp_fused(const float* __restrict__ x,
               const float* __restrict__ W_enc, const float* __restrict__ b_enc,
               const float* __restrict__ W_qh,  const float* __restrict__ b_qh,
               const float* __restrict__ W_lh,  const float* __restrict__ b_lh,
               const float* __restrict__ W_dq,  const float* __restrict__ b_dq,
               const float* __restrict__ W_rh,  const float* __restrict__ b_rh,
               const float* __restrict__ cbk,
               float* __restrict__ out, float* __restrict__ loss_out)
{
    __shared__ __align__(16) float buf0[64 * STRIDE];
    __shared__ __align__(16) float buf1[64 * STRIDE];
    __shared__ __align__(16) float buf2[64 * STRIDE];
    __shared__ float cc[256];
    __shared__ float red_d[256];
    __shared__ int   red_i[256];
    __shared__ float wred[4];

    const int t   = threadIdx.x;
    const int n0  = blockIdx.x * 64;
    const int b   = n0 >> 16;            // HW = 65536 rows per batch image
    const int hw0 = n0 & (HW - 1);
    const size_t base = (size_t)b * 64 * HW + hw0;

    float* r_buf = buf0;   // residual (also reused for codebook chunk / deq)
    float* z_buf = buf1;   // z
    float* q_buf = buf2;   // q / quant

    // stage x tile: r_buf[r][c] = x[b, c, hw0 + r]   (coalesced 64-float runs)
    for (int i = 0; i < 16; ++i) {
        const int e = t + 256 * i;
        const int c = e >> 6, r = e & 63;
        r_buf[r * STRIDE + c] = x[base + (size_t)c * HW + r];
    }

    const int lane_c = t & 63;
    const int g      = t >> 6;   // row group (wave-uniform)
    float restored[16];
    #pragma unroll
    for (int i = 0; i < 16; ++i) restored[i] = 0.f;
    float loss_acc = 0.f;

    __syncthreads();

    for (int L = 0; L < 3; ++L) {
        // z = residual @ W_enc + b_enc
        mat64<0>(z_buf, r_buf, W_enc + L * 4096, b_enc + L * 64, nullptr, nullptr, lane_c, g);
        __syncthreads();
        // q = z @ W_qh + b_qh
        mat64<0>(q_buf, z_buf, W_qh + L * 4096, b_qh + L * 64, nullptr, nullptr, lane_c, g);

        // VQ: per subspace, stage codebook chunk into (dead) r_buf, scan, quantize in place
        for (int s = 0; s < 4; ++s) {
            __syncthreads();   // q_buf visible; prior chunk readers done
            const float4* __restrict__ cbs4 = (const float4*)(cbk + (size_t)(L * 4 + s) * 4096);
            float4* __restrict__ rb4 = (float4*)r_buf;
            #pragma unroll
            for (int i = 0; i < 4; ++i)
                rb4[t + 256 * i] = cbs4[t + 256 * i];
            __syncthreads();
            {   // cc[m] = ||cb[m]||^2, one code per thread
                float s0 = 0, s1 = 0, s2 = 0, s3 = 0;
                const float* cp = r_buf + t * 16;
                #pragma unroll
                for (int d4 = 0; d4 < 4; ++d4) {
                    const float4 v = *(const float4*)(cp + 4 * d4);
                    s0 = fmaf(v.x, v.x, s0); s1 = fmaf(v.y, v.y, s1);
                    s2 = fmaf(v.z, v.z, s2); s3 = fmaf(v.w, v.w, s3);
                }
                cc[t] = (s0 + s1) + (s2 + s3);
            }
            __syncthreads();
            {   // scan: thread = (row, quarter of codes); codebook reads are wave-uniform broadcasts
                const int row = t & 63, qt = t >> 6;
                float qv[16];
                const float* qp = q_buf + row * STRIDE + s * 16;
                #pragma unroll
                for (int d4 = 0; d4 < 4; ++d4) {
                    const float4 v = *(const float4*)(qp + 4 * d4);
                    qv[4 * d4 + 0] = v.x; qv[4 * d4 + 1] = v.y;
                    qv[4 * d4 + 2] = v.z; qv[4 * d4 + 3] = v.w;
                }
                float qq = 0.f;
                #pragma unroll
                for (int d = 0; d < 16; ++d) qq = fmaf(qv[d], qv[d], qq);
                float best = 3.4e38f; int bi = 0;
                #pragma unroll 2
                for (int mi = 0; mi < 64; ++mi) {
                    const int m = qt * 64 + mi;
                    const float* cp = r_buf + m * 16;
                    float d0 = 0, d1 = 0, d2 = 0, d3 = 0;
                    #pragma unroll
                    for (int d4 = 0; d4 < 4; ++d4) {
                        const float4 v = *(const float4*)(cp + 4 * d4);
                        d0 = fmaf(qv[4 * d4 + 0], v.x, d0);
                        d1 = fmaf(qv[4 * d4 + 1], v.y, d1);
                        d2 = fmaf(qv[4 * d4 + 2], v.z, d2);
                        d3 = fmaf(qv[4 * d4 + 3], v.w, d3);
                    }
                    const float dot  = (d0 + d1) + (d2 + d3);
                    const float dist = qq - 2.0f * dot + cc[m];   // same formula as reference
                    if (dist < best) { best = dist; bi = m; }     // strict <  => first-min (jnp argmin)
                }
                red_d[qt * 64 + row] = best;
                red_i[qt * 64 + row] = bi;
            }
            __syncthreads();
            if (t < 64) {   // combine quarters (ascending => lowest index on exact tie), quantize + loss
                const int row = t;
                float best = red_d[row]; int bi = red_i[row];
                #pragma unroll
                for (int qt = 1; qt < 4; ++qt) {
                    const float dv = red_d[qt * 64 + row];
                    if (dv < best) { best = dv; bi = red_i[qt * 64 + row]; }
                }
                float* qp = q_buf + row * STRIDE + s * 16;
                const float* hp = r_buf + bi * 16;
                float lsum = 0.f;
                #pragma unroll
                for (int d = 0; d < 16; ++d) {
                    const float qvv = qp[d];
                    const float hv  = hp[d];
                    const float e   = qvv - hv;
                    lsum = fmaf(e, e, lsum);
                    qp[d] = hv;   // quant = hard (forward value)
                }
                loss_acc += lsum;
            }
        }
        __syncthreads();
        // deq = quant @ W_dq + b_dq  -> r_buf (chunk dead)
        mat64<0>(r_buf, q_buf, W_dq + L * 4096, b_dq + L * 64, nullptr, nullptr, lane_c, g);
        __syncthreads();
        // restored += deq @ W_rh + b_rh   (register accumulator)
        mat64<1>(nullptr, r_buf, W_rh + L * 4096, b_rh + L * 64, nullptr, restored, lane_c, g);
        // residual' = z @ W_lh + b_lh - deq  -> q_buf (becomes next residual)
        if (L < 2)
            mat64<2>(q_buf, z_buf, W_lh + L * 4096, b_lh + L * 64, r_buf, nullptr, lane_c, g);
        __syncthreads();
        float* tmp = r_buf; r_buf = q_buf; q_buf = tmp;
    }

    // loss: wave shuffle-reduce -> LDS -> one atomic per block
    #pragma unroll
    for (int off = 32; off > 0; off >>= 1) loss_acc += __shfl_down(loss_acc, off, 64);
    if ((t & 63) == 0) wred[t >> 6] = loss_acc;

    // restored regs -> z_buf (dead) -> coalesced global store
    #pragma unroll
    for (int r0 = 0; r0 < 16; ++r0)
        z_buf[(g * 16 + r0) * STRIDE + lane_c] = restored[r0];
    __syncthreads();
    for (int i = 0; i < 16; ++i) {
        const int e = t + 256 * i;
        const int c = e >> 6, r = e & 63;
        out[base + (size_t)c * HW + r] = z_buf[r * STRIDE + c];
    }
    if (t == 0) {
        const float tot = (wred[0] + wred[1]) + (wred[2] + wred[3]);
        atomicAdd(loss_out, tot * (1.25f / 16777216.0f));
    }
}

extern "C" void kernel_launch(void* const* d_in, const int* in_sizes, int n_in,
                              void* d_out, int out_size, void* d_ws, size_t ws_size,
                              hipStream_t stream) {
    const float* x     = (const float*)d_in[0];
    const float* W_enc = (const float*)d_in[1];
    const float* b_enc = (const float*)d_in[2];
    const float* W_qh  = (const float*)d_in[3];
    const float* b_qh  = (const float*)d_in[4];
    const float* W_lh  = (const float*)d_in[5];
    const float* b_lh  = (const float*)d_in[6];
    const float* W_dq  = (const float*)d_in[7];
    const float* b_dq  = (const float*)d_in[8];
    const float* W_rh  = (const float*)d_in[9];
    const float* b_rh  = (const float*)d_in[10];
    const float* cbk   = (const float*)d_in[11];

    float* out      = (float*)d_out;
    float* loss_out = out + (out_size - 1);   // outputs concatenated: [B*C*H*W floats][loss]

    // zero the loss accumulator (d_out is poisoned before every timed launch); capture-safe
    hipMemsetAsync(loss_out, 0, sizeof(float), stream);

    hpp_fused<<<dim3(4096), dim3(256), 0, stream>>>(
        x, W_enc, b_enc, W_qh, b_qh, W_lh, b_lh, W_dq, b_dq, W_rh, b_rh,
        cbk, out, loss_out);
}